// Round 1
// baseline (437.945 us; speedup 1.0000x reference)
//
#include <hip/hip_runtime.h>
#include <math.h>

// ---------------------------------------------------------------------------
// GAT 3-layer net. R13 = R12 (374us verified config) + three changes:
//  1. attn dots (layers 1/2) fused into GEMM epilogue at REGISTER level:
//     per-row dot via 4 FMA + 4-step shfl_xor reduce + atomicAdd. This is NOT
//     R11 (extra GEMM columns, which cost an A-sweep) -- no extra tiles.
//     k_attn_dots launches removed; als/ald zeroed via memset before gemms.
//  2. k_agg: 1-ahead register prefetch in gather loop, alpha staging spread
//     over all 256 threads, ald/m/inv cached in LDS.
//  3. k_layer3: col[] prefetched one-ahead to break dependent load chain.
// Core GEMM unchanged: BK=64 128x128 bf16 MFMA, global_load_lds w=16,
// XOR LDS swizzle (0 bank conflicts), XCD-aware 1D grid swizzle, fp8 H.
// ---------------------------------------------------------------------------

__device__ __forceinline__ float leaky(float x){ return x > 0.f ? x : 0.2f * x; }

__device__ __forceinline__ float bf2f(unsigned short u){
  union { unsigned int i; float f; } v; v.i = ((unsigned int)u) << 16; return v.f;
}
__device__ __forceinline__ unsigned short f2bf(float f){
  union { float f; unsigned int i; } v; v.f = f;
  unsigned int r = v.i + 0x7FFF + ((v.i >> 16) & 1);   // RNE
  return (unsigned short)(r >> 16);
}
__device__ __forceinline__ float4 loadbf4(const unsigned short* p){
  ushort4 u = *(const ushort4*)p;
  return make_float4(bf2f(u.x), bf2f(u.y), bf2f(u.z), bf2f(u.w));
}

// ---- fp8 e4m3 helpers (HW cvt; self-consistent round-trip) ----
typedef __attribute__((ext_vector_type(2))) float f2v;
__device__ __forceinline__ unsigned char f2fp8(float x){
  int v = __builtin_amdgcn_cvt_pk_fp8_f32(x, x, 0, false);
  return (unsigned char)(v & 0xff);
}
__device__ __forceinline__ float4 fp8x4(unsigned int u){
  f2v a = __builtin_amdgcn_cvt_pk_f32_fp8((int)u, false);
  f2v b = __builtin_amdgcn_cvt_pk_f32_fp8((int)u, true);
  return make_float4(a.x, a.y, b.x, b.y);
}

// ---------------- mega prep kernel ----------------
__device__ __forceinline__ void tr_tile(const float* __restrict__ W,
                                        unsigned short* __restrict__ Wt,
                                        int K, int N, int rowOff, int lb,
                                        unsigned short tile[32][33]){
  int gx = K >> 5;
  int bk = (lb % gx) << 5;
  int bn = (lb / gx) << 5;
  int tx = threadIdx.x & 31;
  int ty = threadIdx.x >> 5;
#pragma unroll
  for (int r = 0; r < 32; r += 8)
    tile[ty + r][tx] = f2bf(W[(size_t)(bk + ty + r) * N + bn + tx]);
  __syncthreads();
#pragma unroll
  for (int r = 0; r < 32; r += 8)
    Wt[(size_t)(rowOff + bn + ty + r) * K + bk + tx] = tile[tx][ty + r];
}

__global__ __launch_bounds__(256) void k_prep(
    const float* __restrict__ W1, const float* __restrict__ Wl1,
    const float* __restrict__ W2, const float* __restrict__ Wl2,
    const float* __restrict__ W3, const float* __restrict__ Wl3,
    const float* __restrict__ bl3,
    const float* __restrict__ nf, const int* __restrict__ ei,
    unsigned short* __restrict__ Wc1, unsigned short* __restrict__ Wc2,
    unsigned short* __restrict__ Bt3, float* __restrict__ biasc,
    unsigned short* __restrict__ Abf1, unsigned short* __restrict__ Abf2,
    int* __restrict__ deg, int Mpad, int N, int E)
{
  __shared__ unsigned short tile[32][33];
  int lb = blockIdx.x;
  if (lb < 512){ tr_tile(W1, Wc1, 512, 1024, 0, lb, tile); return; }
  lb -= 512;
  if (lb < 512){ tr_tile(Wl1, Wc1, 512, 1024, 1024, lb, tile); return; }
  lb -= 512;
  if (lb < 1024){ tr_tile(W2, Wc2, 1024, 1024, 0, lb, tile); return; }
  lb -= 1024;
  if (lb < 1024){ tr_tile(Wl2, Wc2, 1024, 1024, 1024, lb, tile); return; }
  lb -= 1024;
  if (lb < 512){              // w3fill: Bt3[128][1024] + biasc[48]
    int idx = lb * 256 + threadIdx.x;
    if (idx < 48) biasc[idx] = (idx >= 36 && idx < 42) ? bl3[idx - 36] : 0.f;
    int n = idx >> 10, k = idx & 1023;
    float v = 0.f;
    if (n < 36) v = W3[(size_t)k * 36 + n];
    else if (n < 42) v = Wl3[(size_t)k * 6 + (n - 36)];
    Bt3[idx] = f2bf(v);
    return;
  }
  lb -= 512;
  int cvtBlocks = Mpad >> 1;
  if (lb < cvtBlocks){        // nf fp32 [N,512] -> Abf1 bf16 [Mpad,512]
    int idx = lb * 256 + threadIdx.x;
    int e = idx << 2;
    int row = e >> 9;
    ushort4 o;
    if (row < N){
      float4 v = *(const float4*)(nf + (size_t)row * 512 + (e & 511));
      o.x = f2bf(v.x); o.y = f2bf(v.y); o.z = f2bf(v.z); o.w = f2bf(v.w);
    } else { o.x = o.y = o.z = o.w = 0; }
    *(ushort4*)(Abf1 + e) = o;
    return;
  }
  lb -= cvtBlocks;
  int padBlocks = Mpad - N;
  if (lb < padBlocks){        // zero Abf2 rows N..Mpad
    int idx = lb * 256 + threadIdx.x;
    ushort4 z; z.x = z.y = z.z = z.w = 0;
    *(ushort4*)(Abf2 + (size_t)N * 1024 + (size_t)idx * 4) = z;
    return;
  }
  lb -= padBlocks;
  int e = lb * 256 + threadIdx.x;   // degree count
  if (e < E) atomicAdd(&deg[ei[E + e]], 1);
}

// ---------------- CSR scan + scatter ----------------
__global__ void k_scan(const int* __restrict__ deg, int* __restrict__ rp,
                       int* __restrict__ cur, int n){
  __shared__ int part[1024];
  int t = threadIdx.x;
  int K = (n + 1023) >> 10;
  int vals[16];
  int start = t * K;
  int local = 0;
  for (int j = 0; j < K; j++){
    int idx = start + j;
    int v = (idx < n) ? deg[idx] : 0;
    vals[j] = local;
    local += v;
  }
  part[t] = local;
  __syncthreads();
  for (int off = 1; off < 1024; off <<= 1){
    int v = (t >= off) ? part[t - off] : 0;
    __syncthreads();
    part[t] += v;
    __syncthreads();
  }
  int base = part[t] - local;
  for (int j = 0; j < K; j++){
    int idx = start + j;
    if (idx < n){ rp[idx] = base + vals[j]; cur[idx] = base + vals[j]; }
  }
  if (t == 1023) rp[n] = part[1023];
}

__global__ void k_scatter(const int* __restrict__ ei, int* __restrict__ cur,
                          int* __restrict__ col, int E){
  int e = blockIdx.x * blockDim.x + threadIdx.x;
  if (e < E){
    int s = ei[e], d = ei[E + e];
    int p = atomicAdd(&cur[d], 1);
    col[p] = s;
  }
}

// ---------------- bf16 MFMA GEMM, 128x128 tile, BK=64, LDS XOR swizzle ------
typedef __attribute__((ext_vector_type(8))) short bf8_t;
typedef __attribute__((ext_vector_type(4))) float f4_t;

__device__ __forceinline__ void async16(const unsigned short* g, unsigned short* l){
  __builtin_amdgcn_global_load_lds(
      (const __attribute__((address_space(1))) void*)g,
      (__attribute__((address_space(3))) void*)l, 16, 0, 0);
}

// grid: 8 * Gm * Ntiles (1D); xcd = b&7 owns m-tiles [xcd*Gm, ...)
// fpOut=0 (layers 1/2, Ntot=2048): bn<1024 -> outH fp8 + fused attn dots
//   (register-level: shfl-reduce + atomicAdd into alsv/aldv; MUST be zeroed);
//   bn>=1024 -> outY bf16+bias.
// fpOut=1 (layer 3, Ntot=48): outF fp32 + bias; fused attn3 dots via LDS.
__global__ __launch_bounds__(256) void k_mfma_gemm(
    const unsigned short* __restrict__ A,
    const unsigned short* __restrict__ Bt,
    const float* __restrict__ bias,
    unsigned char* __restrict__ outH,
    unsigned short* __restrict__ outY,
    float* __restrict__ outF,
    const float* __restrict__ asv, const float* __restrict__ adv,
    float* __restrict__ alsv, float* __restrict__ aldv,
    int M, int K, int Ntot, int Mtiles, int Gm, int fpOut)
{
  __shared__ unsigned short SM[2 * 8192];        // 32 KB total
  unsigned short* Asm = SM;                      // 16 KB (two 32-k planes)
  unsigned short* Bsm = SM + 8192;               // 16 KB
  int b = blockIdx.x;
  int xcd = b & 7;
  int j = b >> 3;
  int mloc = j % Gm;
  int n = j / Gm;
  int mtile = xcd * Gm + mloc;
  if (mtile >= Mtiles) return;
  int bm = mtile * 128, bn = n * 128;

  int t = threadIdx.x;
  int w = t >> 6, lane = t & 63;
  int wm = (w >> 1) * 64, wn = (w & 1) * 64;
  int lr = lane & 15, lq = lane >> 4;

  f4_t acc[4][4] = {};

  int srow = lane >> 2;                                   // 0..15 in chunk
  int scol = (((lane & 3) ^ ((lane >> 3) & 3)) << 3);     // swizzled k-chunk
  int sw   = (lr >> 1) & 3;                               // read-side swizzle

  for (int k0 = 0; k0 < K; k0 += 64){
#pragma unroll
    for (int h = 0; h < 2; h++){
#pragma unroll
      for (int r = 0; r < 2; r++){
        int c = r * 4 + w;
        async16(A + (size_t)(bm + c * 16 + srow) * K + k0 + h * 32 + scol,
                &Asm[h * 4096 + c * 512]);
        async16(Bt + (size_t)(bn + c * 16 + srow) * K + k0 + h * 32 + scol,
                &Bsm[h * 4096 + c * 512]);
      }
    }
    __syncthreads();
#pragma unroll
    for (int h = 0; h < 2; h++){
      bf8_t a[4], bfr[4];
#pragma unroll
      for (int i = 0; i < 4; i++)
        a[i] = *(const bf8_t*)&Asm[h * 4096 + (wm + i * 16 + lr) * 32 + (lq ^ sw) * 8];
#pragma unroll
      for (int i = 0; i < 4; i++)
        bfr[i] = *(const bf8_t*)&Bsm[h * 4096 + (wn + i * 16 + lr) * 32 + (lq ^ sw) * 8];
#pragma unroll
      for (int mi = 0; mi < 4; mi++)
#pragma unroll
        for (int ni = 0; ni < 4; ni++)
          acc[mi][ni] = __builtin_amdgcn_mfma_f32_16x16x32_bf16(a[mi], bfr[ni], acc[mi][ni], 0, 0, 0);
    }
    __syncthreads();
  }

  if (fpOut){
    // layer 3: bn==0, Ntot=48. Stage rows into LDS (stride 49) for fused dots.
    float* cl = (float*)SM;
#pragma unroll
    for (int mi = 0; mi < 4; mi++){
#pragma unroll
      for (int ni = 0; ni < 4; ni++){
        int colg = wn + ni * 16 + lr;
        if (colg >= Ntot) continue;
        float bv = bias[colg];
#pragma unroll
        for (int rg = 0; rg < 4; rg++){
          int rowl = wm + mi * 16 + lq * 4 + rg;
          int rowg = bm + rowl;
          float v = acc[mi][ni][rg] + bv;
          cl[rowl * 49 + colg] = v;
          if (rowg < M) outF[(size_t)rowg * Ntot + colg] = v;
        }
      }
    }
    __syncthreads();
    for (int task = t; task < 128 * 6; task += 256){
      int row = task / 6, h = task - row * 6;
      int rowg = bm + row;
      if (rowg < M){
        float s = 0.f, d = 0.f;
#pragma unroll
        for (int c = 0; c < 6; c++){
          float v = cl[row * 49 + h * 6 + c];
          s += v * asv[h * 6 + c];
          d += v * adv[h * 6 + c];
        }
        alsv[rowg * 6 + h] = s;
        aldv[rowg * 6 + h] = d;
      }
    }
  } else if (bn < 1024){
    // H half -> fp8 stores first (drain vmem while we do the shuffles below)
#pragma unroll
    for (int mi = 0; mi < 4; mi++){
#pragma unroll
      for (int ni = 0; ni < 4; ni++){
        int colg = bn + wn + ni * 16 + lr;
#pragma unroll
        for (int rg = 0; rg < 4; rg++){
          int rowg = bm + wm + mi * 16 + lq * 4 + rg;
          if (rowg < M) outH[(size_t)rowg * 1024 + colg] = f2fp8(acc[mi][ni][rg]);
        }
      }
    }
    // fused attn dots: this block covers cols [bn, bn+128) = half of head bn>>8.
    // Per (mi,rg): row fixed across the 16-lane lr-group; dot over the wave's
    // 64 cols = 4 in-register FMAs + 4-step shfl_xor reduce; atomicAdd partial.
    int hd = bn >> 8;
    float wsc[4], wdc[4];
#pragma unroll
    for (int ni = 0; ni < 4; ni++){
      int colg = bn + wn + ni * 16 + lr;
      wsc[ni] = asv[colg];
      wdc[ni] = adv[colg];
    }
#pragma unroll
    for (int mi = 0; mi < 4; mi++){
#pragma unroll
      for (int rg = 0; rg < 4; rg++){
        float ps = 0.f, pd = 0.f;
#pragma unroll
        for (int ni = 0; ni < 4; ni++){
          float v = acc[mi][ni][rg];
          ps += v * wsc[ni];
          pd += v * wdc[ni];
        }
#pragma unroll
        for (int msk = 1; msk < 16; msk <<= 1){
          ps += __shfl_xor(ps, msk);
          pd += __shfl_xor(pd, msk);
        }
        int rowg = bm + wm + mi * 16 + lq * 4 + rg;
        if (lr == 0 && rowg < M){
          atomicAdd(&alsv[rowg * 4 + hd], ps);
          atomicAdd(&aldv[rowg * 4 + hd], pd);
        }
      }
    }
  } else {
    // Y half -> bf16 + bias
#pragma unroll
    for (int mi = 0; mi < 4; mi++){
#pragma unroll
      for (int ni = 0; ni < 4; ni++){
        int colg = bn + wn + ni * 16 + lr - 1024;
        float bv = bias[colg];
#pragma unroll
        for (int rg = 0; rg < 4; rg++){
          int rowg = bm + wm + mi * 16 + lq * 4 + rg;
          if (rowg < M) outY[(size_t)rowg * 1024 + colg] = f2bf(acc[mi][ni][rg] + bv);
        }
      }
    }
  }
}

// ---------------- GAT aggregation (layers 1/2): fp8 H gather + bf16 Y ------
__global__ __launch_bounds__(256) void k_agg(const unsigned char* __restrict__ Hq,
                                             const unsigned short* __restrict__ Y,
                                             unsigned short* __restrict__ Yout,
                                             const float* __restrict__ bias,
                                             const float* __restrict__ als,
                                             const float* __restrict__ ald,
                                             const int* __restrict__ rp,
                                             const int* __restrict__ col){
  int i = blockIdx.x;
  int t = threadIdx.x;
  int lane = t & 63;
  int w = t >> 6;           // head
  int ro = rp[i];
  int deg = rp[i + 1] - ro;
  __shared__ float sm[4], sinv[4], sald[4];
  __shared__ float s_alpha[64][4];
  __shared__ int s_src[64];

  float aldw = ald[i * 4 + w];
  float eself = leaky(als[i * 4 + w] + aldw);
  float m = eself;
  float s = (lane == 0) ? 1.f : 0.f;
  for (int e = lane; e < deg; e += 64){
    int src = col[ro + e];
    float ev = leaky(als[src * 4 + w] + aldw);
    float M = fmaxf(m, ev);
    s = s * __expf(m - M) + __expf(ev - M);
    m = M;
  }
#pragma unroll
  for (int off = 32; off >= 1; off >>= 1){
    float mo = __shfl_down(m, off);
    float so = __shfl_down(s, off);
    float M = fmaxf(m, mo);
    s = s * __expf(m - M) + so * __expf(mo - M);
    m = M;
  }
  if (lane == 0){ sm[w] = m; sinv[w] = 1.f / (s + 1e-16f); sald[w] = aldw; }
  __syncthreads();

  float mh = sm[w];
  float inv = sinv[w];
  float4 acc = loadbf4(Y + (size_t)i * 1024 + t * 4);
  float4 bb  = *(const float4*)(bias + t * 4);
  acc.x += bb.x; acc.y += bb.y; acc.z += bb.z; acc.w += bb.w;
  float aself = __expf(eself - mh) * inv;
  {
    float4 hv = fp8x4(*(const unsigned int*)(Hq + (size_t)i * 1024 + t * 4));
    acc.x += aself * hv.x; acc.y += aself * hv.y;
    acc.z += aself * hv.z; acc.w += aself * hv.w;
  }
  for (int base = 0; base < deg; base += 64){
    __syncthreads();
    int e0 = base + lane;
    if (e0 < deg){
      int src = col[ro + e0];             // redundant across waves; L1-cached
      if (t < 64) s_src[t] = src;
      s_alpha[lane][w] = __expf(leaky(als[src * 4 + w] + sald[w]) - sm[w]) * sinv[w];
    }
    __syncthreads();
    int nn = min(64, deg - base);
    unsigned int u = *(const unsigned int*)(Hq + (size_t)s_src[0] * 1024 + t * 4);
#pragma unroll 2
    for (int e = 0; e < nn; e++){
      float a = s_alpha[e][w];
      float4 hv = fp8x4(u);
      if (e + 1 < nn)
        u = *(const unsigned int*)(Hq + (size_t)s_src[e + 1] * 1024 + t * 4);
      acc.x += a * hv.x; acc.y += a * hv.y; acc.z += a * hv.z; acc.w += a * hv.w;
    }
  }
  acc.x = acc.x > 0.f ? acc.x : expm1f(acc.x);
  acc.y = acc.y > 0.f ? acc.y : expm1f(acc.y);
  acc.z = acc.z > 0.f ? acc.z : expm1f(acc.z);
  acc.w = acc.w > 0.f ? acc.w : expm1f(acc.w);
  ushort4 o;
  o.x = f2bf(acc.x); o.y = f2bf(acc.y); o.z = f2bf(acc.z); o.w = f2bf(acc.w);
  *(ushort4*)(Yout + (size_t)i * 1024 + t * 4) = o;
}

// ---------------- layer 3: GAT(mean heads) + b3 + lin3 + log_softmax ----------------
__global__ __launch_bounds__(64) void k_layer3(const float* __restrict__ comb,
                                               const float* __restrict__ als,
                                               const float* __restrict__ ald,
                                               const float* __restrict__ b3,
                                               const int* __restrict__ rp,
                                               const int* __restrict__ col,
                                               float* __restrict__ out){
  int i = blockIdx.x;
  int lane = threadIdx.x;
  int ro = rp[i], deg = rp[i + 1] - ro;
  float aldv[6], m[6], s[6];
#pragma unroll
  for (int h = 0; h < 6; h++){
    aldv[h] = ald[i * 6 + h];
    float e = leaky(als[i * 6 + h] + aldv[h]);
    m[h] = e;
    s[h] = (lane == 0) ? 1.f : 0.f;
  }
  for (int e = lane; e < deg; e += 64){
    int src = col[ro + e];
#pragma unroll
    for (int h = 0; h < 6; h++){
      float ev = leaky(als[src * 6 + h] + aldv[h]);
      float M = fmaxf(m[h], ev);
      s[h] = s[h] * __expf(m[h] - M) + __expf(ev - M);
      m[h] = M;
    }
  }
#pragma unroll
  for (int off = 32; off >= 1; off >>= 1){
#pragma unroll
    for (int h = 0; h < 6; h++){
      float mo = __shfl_down(m[h], off);
      float so = __shfl_down(s[h], off);
      float M = fmaxf(m[h], mo);
      s[h] = s[h] * __expf(m[h] - M) + so * __expf(mo - M);
      m[h] = M;
    }
  }
#pragma unroll
  for (int h = 0; h < 6; h++){ m[h] = __shfl(m[h], 0); s[h] = __shfl(s[h], 0); }

  __shared__ float o36[36];
  __shared__ float o6[6];
  if (lane < 36){
    int hh = lane / 6, cc = lane - hh * 6;
    float inv = 1.f / (s[hh] + 1e-16f);
    float acc = __expf(leaky(als[i * 6 + hh] + aldv[hh]) - m[hh]) * inv
                * comb[(size_t)i * 48 + hh * 6 + cc];
    int srcN = deg > 0 ? col[ro] : 0;
    for (int e = 0; e < deg; e++){
      int src = srcN;
      if (e + 1 < deg) srcN = col[ro + e + 1];
      float a = __expf(leaky(als[src * 6 + hh] + aldv[hh]) - m[hh]) * inv;
      acc += a * comb[(size_t)src * 48 + hh * 6 + cc];
    }
    o36[lane] = acc;
  }
  __syncthreads();
  if (lane < 6){
    float v = 0.f;
#pragma unroll
    for (int h = 0; h < 6; h++) v += o36[h * 6 + lane];
    o6[lane] = v * (1.f / 6.f) + b3[lane] + comb[(size_t)i * 48 + 36 + lane];
  }
  __syncthreads();
  if (lane == 0){
    float mx = o6[0];
    for (int c = 1; c < 6; c++) mx = fmaxf(mx, o6[c]);
    float se = 0.f;
    for (int c = 0; c < 6; c++) se += __expf(o6[c] - mx);
    float lse = logf(se);
    for (int c = 0; c < 6; c++) out[(size_t)i * 6 + c] = o6[c] - mx - lse;
  }
}

// ---------------------------------------------------------------------------
extern "C" void kernel_launch(void* const* d_in, const int* in_sizes, int n_in,
                              void* d_out, int out_size, void* d_ws, size_t ws_size,
                              hipStream_t stream){
  const float* nf  = (const float*)d_in[0];
  const int*   ei  = (const int*)d_in[1];
  const float* W1  = (const float*)d_in[2];
  const float* as1 = (const float*)d_in[3];
  const float* ad1 = (const float*)d_in[4];
  const float* b1  = (const float*)d_in[5];
  const float* Wl1 = (const float*)d_in[6];
  const float* bl1 = (const float*)d_in[7];
  const float* W2  = (const float*)d_in[8];
  const float* as2 = (const float*)d_in[9];
  const float* ad2 = (const float*)d_in[10];
  const float* b2  = (const float*)d_in[11];
  const float* Wl2 = (const float*)d_in[12];
  const float* bl2 = (const float*)d_in[13];
  const float* W3  = (const float*)d_in[14];
  const float* as3 = (const float*)d_in[15];
  const float* ad3 = (const float*)d_in[16];
  const float* b3  = (const float*)d_in[17];
  const float* Wl3 = (const float*)d_in[18];
  const float* bl3 = (const float*)d_in[19];
  float* out = (float*)d_out;

  const int N = in_sizes[0] / 512;   // 10000
  const int E = in_sizes[1] / 2;     // 160000
  const int Mpad = ((N + 127) / 128) * 128;   // 10112
  const int Mtiles = Mpad / 128;              // 79
  const int Gm = (Mtiles + 7) / 8;            // 10

  char* ws = (char*)d_ws;
  size_t off = 0;
  auto alloc = [&](size_t bytes) -> char* {
    char* p = ws + off;
    off += (bytes + 255) & ~(size_t)255;
    return p;
  };
  unsigned short* Abf1 = (unsigned short*)alloc((size_t)Mpad * 512 * 2);
  unsigned short* Abf2 = (unsigned short*)alloc((size_t)Mpad * 1024 * 2);
  unsigned char*  Hq   = (unsigned char*)alloc((size_t)N * 1024);
  unsigned short* Ybf  = (unsigned short*)alloc((size_t)N * 1024 * 2);
  float* comb   = (float*)alloc((size_t)N * 48 * 4);
  float* als    = (float*)alloc((size_t)N * 8 * 4);
  float* ald    = (float*)alloc((size_t)N * 8 * 4);
  float* biasc  = (float*)alloc(48 * 4);
  int* deg      = (int*)alloc((size_t)N * 4);
  int* rp       = (int*)alloc((size_t)(N + 1) * 4);
  int* cur      = (int*)alloc((size_t)N * 4);
  int* colx     = (int*)alloc((size_t)E * 4);
  unsigned short* Wc1 = (unsigned short*)alloc((size_t)2048 * 512 * 2);
  unsigned short* Wc2 = (unsigned short*)alloc((size_t)2048 * 1024 * 2);
  unsigned short* Bt3 = (unsigned short*)alloc((size_t)128 * 1024 * 2);

  hipMemsetAsync(deg, 0, (size_t)N * 4, stream);
  // zero attn-dot accumulators for layer 1 (GEMM epilogue atomicAdds into them)
  hipMemsetAsync(als, 0, (size_t)N * 4 * sizeof(float), stream);
  hipMemsetAsync(ald, 0, (size_t)N * 4 * sizeof(float), stream);

  int prepBlocks = 512 + 512 + 1024 + 1024 + 512 + (Mpad >> 1) + (Mpad - N)
                 + (E + 255) / 256;
  k_prep<<<prepBlocks, 256, 0, stream>>>(W1, Wl1, W2, Wl2, W3, Wl3, bl3,
                                         nf, ei, Wc1, Wc2, Bt3, biasc,
                                         Abf1, Abf2, deg, Mpad, N, E);
  k_scan   <<<1, 1024, 0, stream>>>(deg, rp, cur, N);
  k_scatter<<<(E + 255) / 256, 256, 0, stream>>>(ei, cur, colx, E);

  int blocksL = 8 * Gm * 16;
  int blocks3 = 8 * Gm * 1;

  // layer 1 (attn dots fused into GEMM epilogue)
  k_mfma_gemm<<<blocksL, 256, 0, stream>>>(Abf1, Wc1, bl1, Hq, Ybf, nullptr,
                                           as1, ad1, als, ald,
                                           N, 512, 2048, Mtiles, Gm, 0);
  k_agg<<<N, 256, 0, stream>>>(Hq, Ybf, Abf2, b1, als, ald, rp, colx);

  // layer 2
  hipMemsetAsync(als, 0, (size_t)N * 4 * sizeof(float), stream);
  hipMemsetAsync(ald, 0, (size_t)N * 4 * sizeof(float), stream);
  k_mfma_gemm<<<blocksL, 256, 0, stream>>>(Abf2, Wc2, bl2, Hq, Ybf, nullptr,
                                           as2, ad2, als, ald,
                                           N, 1024, 2048, Mtiles, Gm, 0);
  k_agg<<<N, 256, 0, stream>>>(Hq, Ybf, Abf2, b2, als, ald, rp, colx);

  // layer 3 (attn3 fused into GEMM epilogue)
  k_mfma_gemm<<<blocks3, 256, 0, stream>>>(Abf2, Bt3, biasc, nullptr, nullptr, comb,
                                           as3, ad3, als, ald,
                                           N, 1024, 48, Mtiles, Gm, 1);
  k_layer3<<<N, 64, 0, stream>>>(comb, als, ald, b3, rp, colx, out);
}

// Round 6
// 404.555 us; speedup vs baseline: 1.0825x; 1.0825x over previous
//
#include <hip/hip_runtime.h>
#include <math.h>

// ---------------------------------------------------------------------------
// GAT 3-layer net. R18 = R14..R17 resubmitted verbatim (none ran: GPU
// acquisition timeouts x4). Changes vs R13 (last measured, 438 us):
//  1. k_mfma_gemm: T3 "minimum 2-phase" double-buffered k-loop. 64 KB LDS
//     (2 x 32KB k-tiles); STAGE(kt+1) issued BEFORE ds_read+MFMA of tile kt;
//     ONE __syncthreads per k-step (its vmcnt(0) drain lands after MFMA, so
//     global_load_lds latency hides under compute). Evidence: R13 rocprof
//     showed GEMM2 93us @ MfmaUtil 18%, HBM 12% -> stall-bound; guide m230/
//     m248: 2ph 128^2 = 666-682 TF vs our measured ~456 TF.
//  2. removed the 4 mid-stream hipMemsetAsync nodes: ping-pong (als,ald)
//     buffer pairs per layer; single up-front memset over contiguous region.
// Unchanged: 128x128 BK=64 bf16 MFMA, global_load_lds w=16, XOR LDS swizzle,
// XCD-aware grid swizzle, fp8 H, fused attn dots in GEMM epilogues.
// ---------------------------------------------------------------------------

__device__ __forceinline__ float leaky(float x){ return x > 0.f ? x : 0.2f * x; }

__device__ __forceinline__ float bf2f(unsigned short u){
  union { unsigned int i; float f; } v; v.i = ((unsigned int)u) << 16; return v.f;
}
__device__ __forceinline__ unsigned short f2bf(float f){
  union { float f; unsigned int i; } v; v.f = f;
  unsigned int r = v.i + 0x7FFF + ((v.i >> 16) & 1);   // RNE
  return (unsigned short)(r >> 16);
}
__device__ __forceinline__ float4 loadbf4(const unsigned short* p){
  ushort4 u = *(const ushort4*)p;
  return make_float4(bf2f(u.x), bf2f(u.y), bf2f(u.z), bf2f(u.w));
}

// ---- fp8 e4m3 helpers (HW cvt; self-consistent round-trip) ----
typedef __attribute__((ext_vector_type(2))) float f2v;
__device__ __forceinline__ unsigned char f2fp8(float x){
  int v = __builtin_amdgcn_cvt_pk_fp8_f32(x, x, 0, false);
  return (unsigned char)(v & 0xff);
}
__device__ __forceinline__ float4 fp8x4(unsigned int u){
  f2v a = __builtin_amdgcn_cvt_pk_f32_fp8((int)u, false);
  f2v b = __builtin_amdgcn_cvt_pk_f32_fp8((int)u, true);
  return make_float4(a.x, a.y, b.x, b.y);
}

// ---------------- mega prep kernel ----------------
__device__ __forceinline__ void tr_tile(const float* __restrict__ W,
                                        unsigned short* __restrict__ Wt,
                                        int K, int N, int rowOff, int lb,
                                        unsigned short tile[32][33]){
  int gx = K >> 5;
  int bk = (lb % gx) << 5;
  int bn = (lb / gx) << 5;
  int tx = threadIdx.x & 31;
  int ty = threadIdx.x >> 5;
#pragma unroll
  for (int r = 0; r < 32; r += 8)
    tile[ty + r][tx] = f2bf(W[(size_t)(bk + ty + r) * N + bn + tx]);
  __syncthreads();
#pragma unroll
  for (int r = 0; r < 32; r += 8)
    Wt[(size_t)(rowOff + bn + ty + r) * K + bk + tx] = tile[tx][ty + r];
}

__global__ __launch_bounds__(256) void k_prep(
    const float* __restrict__ W1, const float* __restrict__ Wl1,
    const float* __restrict__ W2, const float* __restrict__ Wl2,
    const float* __restrict__ W3, const float* __restrict__ Wl3,
    const float* __restrict__ bl3,
    const float* __restrict__ nf, const int* __restrict__ ei,
    unsigned short* __restrict__ Wc1, unsigned short* __restrict__ Wc2,
    unsigned short* __restrict__ Bt3, float* __restrict__ biasc,
    unsigned short* __restrict__ Abf1, unsigned short* __restrict__ Abf2,
    int* __restrict__ deg, int Mpad, int N, int E)
{
  __shared__ unsigned short tile[32][33];
  int lb = blockIdx.x;
  if (lb < 512){ tr_tile(W1, Wc1, 512, 1024, 0, lb, tile); return; }
  lb -= 512;
  if (lb < 512){ tr_tile(Wl1, Wc1, 512, 1024, 1024, lb, tile); return; }
  lb -= 512;
  if (lb < 1024){ tr_tile(W2, Wc2, 1024, 1024, 0, lb, tile); return; }
  lb -= 1024;
  if (lb < 1024){ tr_tile(Wl2, Wc2, 1024, 1024, 1024, lb, tile); return; }
  lb -= 1024;
  if (lb < 512){              // w3fill: Bt3[128][1024] + biasc[48]
    int idx = lb * 256 + threadIdx.x;
    if (idx < 48) biasc[idx] = (idx >= 36 && idx < 42) ? bl3[idx - 36] : 0.f;
    int n = idx >> 10, k = idx & 1023;
    float v = 0.f;
    if (n < 36) v = W3[(size_t)k * 36 + n];
    else if (n < 42) v = Wl3[(size_t)k * 6 + (n - 36)];
    Bt3[idx] = f2bf(v);
    return;
  }
  lb -= 512;
  int cvtBlocks = Mpad >> 1;
  if (lb < cvtBlocks){        // nf fp32 [N,512] -> Abf1 bf16 [Mpad,512]
    int idx = lb * 256 + threadIdx.x;
    int e = idx << 2;
    int row = e >> 9;
    ushort4 o;
    if (row < N){
      float4 v = *(const float4*)(nf + (size_t)row * 512 + (e & 511));
      o.x = f2bf(v.x); o.y = f2bf(v.y); o.z = f2bf(v.z); o.w = f2bf(v.w);
    } else { o.x = o.y = o.z = o.w = 0; }
    *(ushort4*)(Abf1 + e) = o;
    return;
  }
  lb -= cvtBlocks;
  int padBlocks = Mpad - N;
  if (lb < padBlocks){        // zero Abf2 rows N..Mpad
    int idx = lb * 256 + threadIdx.x;
    ushort4 z; z.x = z.y = z.z = z.w = 0;
    *(ushort4*)(Abf2 + (size_t)N * 1024 + (size_t)idx * 4) = z;
    return;
  }
  lb -= padBlocks;
  int e = lb * 256 + threadIdx.x;   // degree count
  if (e < E) atomicAdd(&deg[ei[E + e]], 1);
}

// ---------------- CSR scan + scatter ----------------
__global__ void k_scan(const int* __restrict__ deg, int* __restrict__ rp,
                       int* __restrict__ cur, int n){
  __shared__ int part[1024];
  int t = threadIdx.x;
  int K = (n + 1023) >> 10;
  int vals[16];
  int start = t * K;
  int local = 0;
  for (int j = 0; j < K; j++){
    int idx = start + j;
    int v = (idx < n) ? deg[idx] : 0;
    vals[j] = local;
    local += v;
  }
  part[t] = local;
  __syncthreads();
  for (int off = 1; off < 1024; off <<= 1){
    int v = (t >= off) ? part[t - off] : 0;
    __syncthreads();
    part[t] += v;
    __syncthreads();
  }
  int base = part[t] - local;
  for (int j = 0; j < K; j++){
    int idx = start + j;
    if (idx < n){ rp[idx] = base + vals[j]; cur[idx] = base + vals[j]; }
  }
  if (t == 1023) rp[n] = part[1023];
}

__global__ void k_scatter(const int* __restrict__ ei, int* __restrict__ cur,
                          int* __restrict__ col, int E){
  int e = blockIdx.x * blockDim.x + threadIdx.x;
  if (e < E){
    int s = ei[e], d = ei[E + e];
    int p = atomicAdd(&cur[d], 1);
    col[p] = s;
  }
}

// ---------------- bf16 MFMA GEMM, 128x128 tile, BK=64, LDS XOR swizzle ------
// 2-phase double-buffered k-loop (64 KB LDS).
typedef __attribute__((ext_vector_type(8))) short bf8_t;
typedef __attribute__((ext_vector_type(4))) float f4_t;

__device__ __forceinline__ void async16(const unsigned short* g, unsigned short* l){
  __builtin_amdgcn_global_load_lds(
      (const __attribute__((address_space(1))) void*)g,
      (__attribute__((address_space(3))) void*)l, 16, 0, 0);
}

// grid: 8 * Gm * Ntiles (1D); xcd = b&7 owns m-tiles [xcd*Gm, ...)
// fpOut=0 (layers 1/2, Ntot=2048): bn<1024 -> outH fp8 + fused attn dots
//   (register-level: shfl-reduce + atomicAdd into alsv/aldv; MUST be zeroed);
//   bn>=1024 -> outY bf16+bias.
// fpOut=1 (layer 3, Ntot=48): outF fp32 + bias; fused attn3 dots via LDS
//   (writes als/ald directly, no zeroing needed).
__global__ __launch_bounds__(256) void k_mfma_gemm(
    const unsigned short* __restrict__ A,
    const unsigned short* __restrict__ Bt,
    const float* __restrict__ bias,
    unsigned char* __restrict__ outH,
    unsigned short* __restrict__ outY,
    float* __restrict__ outF,
    const float* __restrict__ asv, const float* __restrict__ adv,
    float* __restrict__ alsv, float* __restrict__ aldv,
    int M, int K, int Ntot, int Mtiles, int Gm, int fpOut)
{
  __shared__ unsigned short SM[4 * 8192];        // 64 KB: 2 buffers x (A 16KB + B 16KB)
  int b = blockIdx.x;
  int xcd = b & 7;
  int j = b >> 3;
  int mloc = j % Gm;
  int n = j / Gm;
  int mtile = xcd * Gm + mloc;
  if (mtile >= Mtiles) return;
  int bm = mtile * 128, bn = n * 128;

  int t = threadIdx.x;
  int w = t >> 6, lane = t & 63;
  int wm = (w >> 1) * 64, wn = (w & 1) * 64;
  int lr = lane & 15, lq = lane >> 4;

  f4_t acc[4][4] = {};

  int srow = lane >> 2;                                   // 0..15 in chunk
  int scol = (((lane & 3) ^ ((lane >> 3) & 3)) << 3);     // swizzled k-chunk
  int sw   = (lr >> 1) & 3;                               // read-side swizzle

  auto stage = [&](int bufOff, int k0){
#pragma unroll
    for (int h = 0; h < 2; h++){
#pragma unroll
      for (int r = 0; r < 2; r++){
        int c = r * 4 + w;
        async16(A + (size_t)(bm + c * 16 + srow) * K + k0 + h * 32 + scol,
                &SM[bufOff + h * 4096 + c * 512]);
        async16(Bt + (size_t)(bn + c * 16 + srow) * K + k0 + h * 32 + scol,
                &SM[bufOff + 8192 + h * 4096 + c * 512]);
      }
    }
  };

  int nt = K >> 6;
  stage(0, 0);
  __syncthreads();                 // vmcnt(0) drain: buf0 ready
  int cur = 0;
  for (int kt = 0; kt < nt; ++kt){
    if (kt + 1 < nt) stage((cur ^ 1) << 14, (kt + 1) << 6);   // loads fly under MFMA
    int aOff = cur << 14, bOff = aOff + 8192;
#pragma unroll
    for (int h = 0; h < 2; h++){
      bf8_t a[4], bfr[4];
#pragma unroll
      for (int i = 0; i < 4; i++)
        a[i] = *(const bf8_t*)&SM[aOff + h * 4096 + (wm + i * 16 + lr) * 32 + (lq ^ sw) * 8];
#pragma unroll
      for (int i = 0; i < 4; i++)
        bfr[i] = *(const bf8_t*)&SM[bOff + h * 4096 + (wn + i * 16 + lr) * 32 + (lq ^ sw) * 8];
#pragma unroll
      for (int mi = 0; mi < 4; mi++)
#pragma unroll
        for (int ni = 0; ni < 4; ni++)
          acc[mi][ni] = __builtin_amdgcn_mfma_f32_16x16x32_bf16(a[mi], bfr[ni], acc[mi][ni], 0, 0, 0);
    }
    __syncthreads();   // drains vmcnt(0) AFTER MFMA: next buf staged, cur reads done
    cur ^= 1;
  }

  if (fpOut){
    // layer 3: bn==0, Ntot=48. Stage rows into LDS (stride 49) for fused dots.
    float* cl = (float*)SM;
#pragma unroll
    for (int mi = 0; mi < 4; mi++){
#pragma unroll
      for (int ni = 0; ni < 4; ni++){
        int colg = wn + ni * 16 + lr;
        if (colg >= Ntot) continue;
        float bv = bias[colg];
#pragma unroll
        for (int rg = 0; rg < 4; rg++){
          int rowl = wm + mi * 16 + lq * 4 + rg;
          int rowg = bm + rowl;
          float v = acc[mi][ni][rg] + bv;
          cl[rowl * 49 + colg] = v;
          if (rowg < M) outF[(size_t)rowg * Ntot + colg] = v;
        }
      }
    }
    __syncthreads();
    for (int task = t; task < 128 * 6; task += 256){
      int row = task / 6, h = task - row * 6;
      int rowg = bm + row;
      if (rowg < M){
        float s = 0.f, d = 0.f;
#pragma unroll
        for (int c = 0; c < 6; c++){
          float v = cl[row * 49 + h * 6 + c];
          s += v * asv[h * 6 + c];
          d += v * adv[h * 6 + c];
        }
        alsv[rowg * 6 + h] = s;
        aldv[rowg * 6 + h] = d;
      }
    }
  } else if (bn < 1024){
    // H half -> fp8 stores first (drain vmem while we do the shuffles below)
#pragma unroll
    for (int mi = 0; mi < 4; mi++){
#pragma unroll
      for (int ni = 0; ni < 4; ni++){
        int colg = bn + wn + ni * 16 + lr;
#pragma unroll
        for (int rg = 0; rg < 4; rg++){
          int rowg = bm + wm + mi * 16 + lq * 4 + rg;
          if (rowg < M) outH[(size_t)rowg * 1024 + colg] = f2fp8(acc[mi][ni][rg]);
        }
      }
    }
    // fused attn dots: this block covers cols [bn, bn+128) = half of head bn>>8.
    int hd = bn >> 8;
    float wsc[4], wdc[4];
#pragma unroll
    for (int ni = 0; ni < 4; ni++){
      int colg = bn + wn + ni * 16 + lr;
      wsc[ni] = asv[colg];
      wdc[ni] = adv[colg];
    }
#pragma unroll
    for (int mi = 0; mi < 4; mi++){
#pragma unroll
      for (int rg = 0; rg < 4; rg++){
        float ps = 0.f, pd = 0.f;
#pragma unroll
        for (int ni = 0; ni < 4; ni++){
          float v = acc[mi][ni][rg];
          ps += v * wsc[ni];
          pd += v * wdc[ni];
        }
#pragma unroll
        for (int msk = 1; msk < 16; msk <<= 1){
          ps += __shfl_xor(ps, msk);
          pd += __shfl_xor(pd, msk);
        }
        int rowg = bm + wm + mi * 16 + lq * 4 + rg;
        if (lr == 0 && rowg < M){
          atomicAdd(&alsv[rowg * 4 + hd], ps);
          atomicAdd(&aldv[rowg * 4 + hd], pd);
        }
      }
    }
  } else {
    // Y half -> bf16 + bias
#pragma unroll
    for (int mi = 0; mi < 4; mi++){
#pragma unroll
      for (int ni = 0; ni < 4; ni++){
        int colg = bn + wn + ni * 16 + lr - 1024;
        float bv = bias[colg];
#pragma unroll
        for (int rg = 0; rg < 4; rg++){
          int rowg = bm + wm + mi * 16 + lq * 4 + rg;
          if (rowg < M) outY[(size_t)rowg * 1024 + colg] = f2bf(acc[mi][ni][rg] + bv);
        }
      }
    }
  }
}

// ---------------- GAT aggregation (layers 1/2): fp8 H gather + bf16 Y ------
__global__ __launch_bounds__(256) void k_agg(const unsigned char* __restrict__ Hq,
                                             const unsigned short* __restrict__ Y,
                                             unsigned short* __restrict__ Yout,
                                             const float* __restrict__ bias,
                                             const float* __restrict__ als,
                                             const float* __restrict__ ald,
                                             const int* __restrict__ rp,
                                             const int* __restrict__ col){
  int i = blockIdx.x;
  int t = threadIdx.x;
  int lane = t & 63;
  int w = t >> 6;           // head
  int ro = rp[i];
  int deg = rp[i + 1] - ro;
  __shared__ float sm[4], sinv[4], sald[4];
  __shared__ float s_alpha[64][4];
  __shared__ int s_src[64];

  float aldw = ald[i * 4 + w];
  float eself = leaky(als[i * 4 + w] + aldw);
  float m = eself;
  float s = (lane == 0) ? 1.f : 0.f;
  for (int e = lane; e < deg; e += 64){
    int src = col[ro + e];
    float ev = leaky(als[src * 4 + w] + aldw);
    float M = fmaxf(m, ev);
    s = s * __expf(m - M) + __expf(ev - M);
    m = M;
  }
#pragma unroll
  for (int off = 32; off >= 1; off >>= 1){
    float mo = __shfl_down(m, off);
    float so = __shfl_down(s, off);
    float M = fmaxf(m, mo);
    s = s * __expf(m - M) + so * __expf(mo - M);
    m = M;
  }
  if (lane == 0){ sm[w] = m; sinv[w] = 1.f / (s + 1e-16f); sald[w] = aldw; }
  __syncthreads();

  float mh = sm[w];
  float inv = sinv[w];
  float4 acc = loadbf4(Y + (size_t)i * 1024 + t * 4);
  float4 bb  = *(const float4*)(bias + t * 4);
  acc.x += bb.x; acc.y += bb.y; acc.z += bb.z; acc.w += bb.w;
  float aself = __expf(eself - mh) * inv;
  {
    float4 hv = fp8x4(*(const unsigned int*)(Hq + (size_t)i * 1024 + t * 4));
    acc.x += aself * hv.x; acc.y += aself * hv.y;
    acc.z += aself * hv.z; acc.w += aself * hv.w;
  }
  for (int base = 0; base < deg; base += 64){
    __syncthreads();
    int e0 = base + lane;
    if (e0 < deg){
      int src = col[ro + e0];             // redundant across waves; L1-cached
      if (t < 64) s_src[t] = src;
      s_alpha[lane][w] = __expf(leaky(als[src * 4 + w] + sald[w]) - sm[w]) * sinv[w];
    }
    __syncthreads();
    int nn = min(64, deg - base);
    unsigned int u = *(const unsigned int*)(Hq + (size_t)s_src[0] * 1024 + t * 4);
#pragma unroll 2
    for (int e = 0; e < nn; e++){
      float a = s_alpha[e][w];
      float4 hv = fp8x4(u);
      if (e + 1 < nn)
        u = *(const unsigned int*)(Hq + (size_t)s_src[e + 1] * 1024 + t * 4);
      acc.x += a * hv.x; acc.y += a * hv.y; acc.z += a * hv.z; acc.w += a * hv.w;
    }
  }
  acc.x = acc.x > 0.f ? acc.x : expm1f(acc.x);
  acc.y = acc.y > 0.f ? acc.y : expm1f(acc.y);
  acc.z = acc.z > 0.f ? acc.z : expm1f(acc.z);
  acc.w = acc.w > 0.f ? acc.w : expm1f(acc.w);
  ushort4 o;
  o.x = f2bf(acc.x); o.y = f2bf(acc.y); o.z = f2bf(acc.z); o.w = f2bf(acc.w);
  *(ushort4*)(Yout + (size_t)i * 1024 + t * 4) = o;
}

// ---------------- layer 3: GAT(mean heads) + b3 + lin3 + log_softmax ----------------
__global__ __launch_bounds__(64) void k_layer3(const float* __restrict__ comb,
                                               const float* __restrict__ als,
                                               const float* __restrict__ ald,
                                               const float* __restrict__ b3,
                                               const int* __restrict__ rp,
                                               const int* __restrict__ col,
                                               float* __restrict__ out){
  int i = blockIdx.x;
  int lane = threadIdx.x;
  int ro = rp[i], deg = rp[i + 1] - ro;
  float aldv[6], m[6], s[6];
#pragma unroll
  for (int h = 0; h < 6; h++){
    aldv[h] = ald[i * 6 + h];
    float e = leaky(als[i * 6 + h] + aldv[h]);
    m[h] = e;
    s[h] = (lane == 0) ? 1.f : 0.f;
  }
  for (int e = lane; e < deg; e += 64){
    int src = col[ro + e];
#pragma unroll
    for (int h = 0; h < 6; h++){
      float ev = leaky(als[src * 6 + h] + aldv[h]);
      float M = fmaxf(m[h], ev);
      s[h] = s[h] * __expf(m[h] - M) + __expf(ev - M);
      m[h] = M;
    }
  }
#pragma unroll
  for (int off = 32; off >= 1; off >>= 1){
#pragma unroll
    for (int h = 0; h < 6; h++){
      float mo = __shfl_down(m[h], off);
      float so = __shfl_down(s[h], off);
      float M = fmaxf(m[h], mo);
      s[h] = s[h] * __expf(m[h] - M) + so * __expf(mo - M);
      m[h] = M;
    }
  }
#pragma unroll
  for (int h = 0; h < 6; h++){ m[h] = __shfl(m[h], 0); s[h] = __shfl(s[h], 0); }

  __shared__ float o36[36];
  __shared__ float o6[6];
  if (lane < 36){
    int hh = lane / 6, cc = lane - hh * 6;
    float inv = 1.f / (s[hh] + 1e-16f);
    float acc = __expf(leaky(als[i * 6 + hh] + aldv[hh]) - m[hh]) * inv
                * comb[(size_t)i * 48 + hh * 6 + cc];
    int srcN = deg > 0 ? col[ro] : 0;
    for (int e = 0; e < deg; e++){
      int src = srcN;
      if (e + 1 < deg) srcN = col[ro + e + 1];
      float a = __expf(leaky(als[src * 6 + hh] + aldv[hh]) - m[hh]) * inv;
      acc += a * comb[(size_t)src * 48 + hh * 6 + cc];
    }
    o36[lane] = acc;
  }
  __syncthreads();
  if (lane < 6){
    float v = 0.f;
#pragma unroll
    for (int h = 0; h < 6; h++) v += o36[h * 6 + lane];
    o6[lane] = v * (1.f / 6.f) + b3[lane] + comb[(size_t)i * 48 + 36 + lane];
  }
  __syncthreads();
  if (lane == 0){
    float mx = o6[0];
    for (int c = 1; c < 6; c++) mx = fmaxf(mx, o6[c]);
    float se = 0.f;
    for (int c = 0; c < 6; c++) se += __expf(o6[c] - mx);
    float lse = logf(se);
    for (int c = 0; c < 6; c++) out[(size_t)i * 6 + c] = o6[c] - mx - lse;
  }
}

// ---------------------------------------------------------------------------
extern "C" void kernel_launch(void* const* d_in, const int* in_sizes, int n_in,
                              void* d_out, int out_size, void* d_ws, size_t ws_size,
                              hipStream_t stream){
  const float* nf  = (const float*)d_in[0];
  const int*   ei  = (const int*)d_in[1];
  const float* W1  = (const float*)d_in[2];
  const float* as1 = (const float*)d_in[3];
  const float* ad1 = (const float*)d_in[4];
  const float* b1  = (const float*)d_in[5];
  const float* Wl1 = (const float*)d_in[6];
  const float* bl1 = (const float*)d_in[7];
  const float* W2  = (const float*)d_in[8];
  const float* as2 = (const float*)d_in[9];
  const float* ad2 = (const float*)d_in[10];
  const float* b2  = (const float*)d_in[11];
  const float* Wl2 = (const float*)d_in[12];
  const float* bl2 = (const float*)d_in[13];
  const float* W3  = (const float*)d_in[14];
  const float* as3 = (const float*)d_in[15];
  const float* ad3 = (const float*)d_in[16];
  const float* b3  = (const float*)d_in[17];
  const float* Wl3 = (const float*)d_in[18];
  const float* bl3 = (const float*)d_in[19];
  float* out = (float*)d_out;

  const int N = in_sizes[0] / 512;   // 10000
  const int E = in_sizes[1] / 2;     // 160000
  const int Mpad = ((N + 127) / 128) * 128;   // 10112
  const int Mtiles = Mpad / 128;              // 79
  const int Gm = (Mtiles + 7) / 8;            // 10

  char* ws = (char*)d_ws;
  size_t off = 0;
  auto alloc = [&](size_t bytes) -> char* {
    char* p = ws + off;
    off += (bytes + 255) & ~(size_t)255;
    return p;
  };
  unsigned short* Abf1 = (unsigned short*)alloc((size_t)Mpad * 512 * 2);
  unsigned short* Abf2 = (unsigned short*)alloc((size_t)Mpad * 1024 * 2);
  unsigned char*  Hq   = (unsigned char*)alloc((size_t)N * 1024);
  unsigned short* Ybf  = (unsigned short*)alloc((size_t)N * 1024 * 2);
  float* comb   = (float*)alloc((size_t)N * 48 * 4);
  // contiguous zero region: deg + (als,ald) ping-pong pairs -> ONE memset
  size_t zbytes = (size_t)N * 4 + 4 * (size_t)N * 4 * 4;   // deg + 4 arrays
  char*  zbase  = alloc(zbytes);
  int*   deg    = (int*)zbase;
  float* als_a  = (float*)(zbase + (size_t)N * 4);
  float* ald_a  = als_a + (size_t)N * 4;
  float* als_b  = ald_a + (size_t)N * 4;
  float* ald_b  = als_b + (size_t)N * 4;
  float* als3   = (float*)alloc((size_t)N * 6 * 4);   // written, not accumulated
  float* ald3   = (float*)alloc((size_t)N * 6 * 4);
  float* biasc  = (float*)alloc(48 * 4);
  int* rp       = (int*)alloc((size_t)(N + 1) * 4);
  int* cur      = (int*)alloc((size_t)N * 4);
  int* colx     = (int*)alloc((size_t)E * 4);
  unsigned short* Wc1 = (unsigned short*)alloc((size_t)2048 * 512 * 2);
  unsigned short* Wc2 = (unsigned short*)alloc((size_t)2048 * 1024 * 2);
  unsigned short* Bt3 = (unsigned short*)alloc((size_t)128 * 1024 * 2);

  hipMemsetAsync(zbase, 0, zbytes, stream);

  int prepBlocks = 512 + 512 + 1024 + 1024 + 512 + (Mpad >> 1) + (Mpad - N)
                 + (E + 255) / 256;
  k_prep<<<prepBlocks, 256, 0, stream>>>(W1, Wl1, W2, Wl2, W3, Wl3, bl3,
                                         nf, ei, Wc1, Wc2, Bt3, biasc,
                                         Abf1, Abf2, deg, Mpad, N, E);
  k_scan   <<<1, 1024, 0, stream>>>(deg, rp, cur, N);
  k_scatter<<<(E + 255) / 256, 256, 0, stream>>>(ei, cur, colx, E);

  int blocksL = 8 * Gm * 16;
  int blocks3 = 8 * Gm * 1;

  // layer 1 (attn dots fused into GEMM epilogue -> als_a/ald_a)
  k_mfma_gemm<<<blocksL, 256, 0, stream>>>(Abf1, Wc1, bl1, Hq, Ybf, nullptr,
                                           as1, ad1, als_a, ald_a,
                                           N, 512, 2048, Mtiles, Gm, 0);
  k_agg<<<N, 256, 0, stream>>>(Hq, Ybf, Abf2, b1, als_a, ald_a, rp, colx);

  // layer 2 (dots -> als_b/ald_b, pre-zeroed; no mid-stream memset)
  k_mfma_gemm<<<blocksL, 256, 0, stream>>>(Abf2, Wc2, bl2, Hq, Ybf, nullptr,
                                           as2, ad2, als_b, ald_b,
                                           N, 1024, 2048, Mtiles, Gm, 0);
  k_agg<<<N, 256, 0, stream>>>(Hq, Ybf, Abf2, b2, als_b, ald_b, rp, colx);

  // layer 3 (attn3 fused into GEMM epilogue; epilogue WRITES als3/ald3)
  k_mfma_gemm<<<blocks3, 256, 0, stream>>>(Abf2, Bt3, biasc, nullptr, nullptr, comb,
                                           as3, ad3, als3, ald3,
                                           N, 1024, 48, Mtiles, Gm, 1);
  k_layer3<<<N, 64, 0, stream>>>(comb, als3, ald3, b3, rp, colx, out);
}